// Round 1
// baseline (41.587 us; speedup 1.0000x reference)
//
#include <hip/hip_runtime.h>

#define G_ 1024
#define DIN_ 3072
#define B_ 8192
#define TB 4

// ---------------------------------------------------------------------------
// Kernel 1: per-group coefficient precompute.
// out[b,g,m] = sum_p w[g,p] * signal_m(perm_p(gated)) where gated_i = u_i*x_i + v_i.
// signal_0 = a ; signal_1 = c + a*b - a*c ; signal_2 = b - a*b + a*c
// All are degree-2 polynomials in gated -> fold softmax + perms + gating into
// 7 coefficients per (g,m): K, Cx0..2, Cq01, Cq02, Cq12 (in x-space).
// Layout: coef[g*24 + m*8 + {0..6}] (8-float stride for float4 loads).
// ---------------------------------------------------------------------------
__global__ __launch_bounds__(256) void fredkin_coef_kernel(
    const int* __restrict__ conn, const float* __restrict__ sel,
    const float* __restrict__ wg, float* __restrict__ coef)
{
    int g = blockIdx.x * blockDim.x + threadIdx.x;
    if (g >= G_) return;

    float u[3], v[3];
#pragma unroll
    for (int i = 0; i < 3; ++i) {
        float s = sel[g * 3 + i];
        float C = s / (1.0f + fabsf(s));
        float a = fabsf(C);
        u[i] = 1.0f - a;          // multiplier on x
        v[i] = 0.5f * (C + a);    // additive bias
    }

    // softmax over the 6 permutation weights
    float w[6];
    float mx = -1e30f;
#pragma unroll
    for (int p = 0; p < 6; ++p) mx = fmaxf(mx, wg[g * 6 + p]);
    float sum = 0.0f;
#pragma unroll
    for (int p = 0; p < 6; ++p) { w[p] = expf(wg[g * 6 + p] - mx); sum += w[p]; }
    float inv = 1.0f / sum;
#pragma unroll
    for (int p = 0; p < 6; ++p) w[p] *= inv;

    // itertools.permutations(range(3)) order
    const int P[6][3] = {{0,1,2},{0,2,1},{1,0,2},{1,2,0},{2,0,1},{2,1,0}};
    // L[m][i]: coeff on gated_i ; Q[m][pair]: coeff on gated_i*gated_j,
    // pair index (0,1)->0 (0,2)->1 (1,2)->2  (== i+j-1 for i<j, symmetric)
    float L[3][3] = {{0.f,0.f,0.f},{0.f,0.f,0.f},{0.f,0.f,0.f}};
    float Q[3][3] = {{0.f,0.f,0.f},{0.f,0.f,0.f},{0.f,0.f,0.f}};
#pragma unroll
    for (int p = 0; p < 6; ++p) {
        int i0 = P[p][0], i1 = P[p][1], i2 = P[p][2];
        float wp = w[p];
        int p01 = i0 + i1 - 1;
        int p02 = i0 + i2 - 1;
        L[0][i0] += wp;                                   // m0: a
        L[1][i2] += wp; Q[1][p01] += wp; Q[1][p02] -= wp; // m1: c + ab - ac
        L[2][i1] += wp; Q[2][p01] -= wp; Q[2][p02] += wp; // m2: b - ab + ac
    }

    // substitute gated_i = u_i*x_i + v_i  ->  x-space coefficients
#pragma unroll
    for (int m = 0; m < 3; ++m) {
        float K = L[m][0]*v[0] + L[m][1]*v[1] + L[m][2]*v[2]
                + Q[m][0]*v[0]*v[1] + Q[m][1]*v[0]*v[2] + Q[m][2]*v[1]*v[2];
        float cx0 = u[0]*(L[m][0] + Q[m][0]*v[1] + Q[m][1]*v[2]);
        float cx1 = u[1]*(L[m][1] + Q[m][0]*v[0] + Q[m][2]*v[2]);
        float cx2 = u[2]*(L[m][2] + Q[m][1]*v[0] + Q[m][2]*v[1]);
        float cq01 = Q[m][0]*u[0]*u[1];
        float cq02 = Q[m][1]*u[0]*u[2];
        float cq12 = Q[m][2]*u[1]*u[2];
        float* o = coef + (size_t)g * 24 + m * 8;
        o[0]=K; o[1]=cx0; o[2]=cx1; o[3]=cx2; o[4]=cq01; o[5]=cq02; o[6]=cq12; o[7]=0.f;
    }
}

// ---------------------------------------------------------------------------
// Kernel 2: streaming evaluation. One block = TB rows of x staged in LDS
// (coalesced float4 loads), 256 threads x 4 groups each. The random column
// gather hits LDS, not L1/L2. Writes are lane-contiguous 12 B chunks.
// ---------------------------------------------------------------------------
__global__ __launch_bounds__(256) void fredkin_main_kernel(
    const float* __restrict__ x, const int* __restrict__ conn,
    const float* __restrict__ coef, float* __restrict__ out)
{
    __shared__ float xs[TB * DIN_];   // 48 KiB -> 3 blocks/CU
    const int t = threadIdx.x;
    const int row0 = blockIdx.x * TB;

    // stage TB rows, coalesced
    const float4* xv = (const float4*)(x + (size_t)row0 * DIN_);
    float4* sv = (float4*)xs;
#pragma unroll
    for (int i = 0; i < (TB * DIN_ / 4) / 256; ++i)   // 12 iters
        sv[t + i * 256] = xv[t + i * 256];
    __syncthreads();

    for (int gi = 0; gi < G_ / 256; ++gi) {
        const int g = t + gi * 256;
        const int c0 = conn[g * 3 + 0];
        const int c1 = conn[g * 3 + 1];
        const int c2 = conn[g * 3 + 2];
        const float4* cf = (const float4*)(coef + (size_t)g * 24);
        const float4 a0 = cf[0], q0 = cf[1];
        const float4 a1 = cf[2], q1 = cf[3];
        const float4 a2 = cf[4], q2 = cf[5];
#pragma unroll
        for (int r = 0; r < TB; ++r) {
            const float x0 = xs[r * DIN_ + c0];
            const float x1 = xs[r * DIN_ + c1];
            const float x2 = xs[r * DIN_ + c2];
            const float p01 = x0 * x1, p02 = x0 * x2, p12 = x1 * x2;
            float o0 = a0.x + a0.y*x0 + a0.z*x1 + a0.w*x2 + q0.x*p01 + q0.y*p02 + q0.z*p12;
            float o1 = a1.x + a1.y*x0 + a1.z*x1 + a1.w*x2 + q1.x*p01 + q1.y*p02 + q1.z*p12;
            float o2 = a2.x + a2.y*x0 + a2.z*x1 + a2.w*x2 + q2.x*p01 + q2.y*p02 + q2.z*p12;
            const size_t off = (size_t)(row0 + r) * (3 * G_) + 3 * g;
            out[off + 0] = o0;
            out[off + 1] = o1;
            out[off + 2] = o2;
        }
    }
}

extern "C" void kernel_launch(void* const* d_in, const int* in_sizes, int n_in,
                              void* d_out, int out_size, void* d_ws, size_t ws_size,
                              hipStream_t stream) {
    const float* x    = (const float*)d_in[0];
    const int*   conn = (const int*)d_in[1];
    const float* sel  = (const float*)d_in[2];
    const float* wg   = (const float*)d_in[3];
    float* out  = (float*)d_out;
    float* coef = (float*)d_ws;   // G_*24 floats = 96 KiB

    hipLaunchKernelGGL(fredkin_coef_kernel, dim3(G_ / 256), dim3(256), 0, stream,
                       conn, sel, wg, coef);
    hipLaunchKernelGGL(fredkin_main_kernel, dim3(B_ / TB), dim3(256), 0, stream,
                       x, conn, coef, out);
}